// Round 7
// baseline (5957.916 us; speedup 1.0000x reference)
//
#include <hip/hip_runtime.h>
#include <math.h>

#define N_NEU    2048
#define BB       64
#define TT       100
#define KIN      784
#define NIN_NEU  1024
#define N_OUT    10
#define NOUT_NEU 128

typedef unsigned int u32;
typedef unsigned long long u64;
typedef unsigned short u16;

// ---------------- prep ----------------
__global__ void k_prep(const float* __restrict__ tau, double* __restrict__ d_syn,
                       double* __restrict__ e_tau){
    int n = blockIdx.x * blockDim.x + threadIdx.x;
    if(n < N_NEU){
        double tv = (double)tau[n];
        d_syn[n] = exp(-1.0 / tv);
        e_tau[n] = 2.718281828459045 / tv;   // np.e / tau
    }
}

// zero projG + exch (ws is poisoned 0xAA; exch tags MUST be 0 at every launch)
__global__ void k_zero(double* __restrict__ p, long nels, u64* __restrict__ exch, int nexch){
    long i = (long)blockIdx.x * blockDim.x + threadIdx.x;
    long stride = (long)gridDim.x * blockDim.x;
    for(; i < nels; i += stride) p[i] = 0.0;
    int j = blockIdx.x * blockDim.x + threadIdx.x;
    if(j < nexch) exch[j] = 0ull;
}

// ---------------- W transpose: Wt[m][n] = Wrec[n][m] ----------------
__global__ __launch_bounds__(256) void k_tr(const float* __restrict__ Wrec, float* __restrict__ Wt){
    __shared__ float tile[32][33];
    int bx = blockIdx.x, by = blockIdx.y;
    int txx = threadIdx.x, tyy = threadIdx.y;          // (32, 8)
    #pragma unroll
    for(int j=0;j<4;j++)
        tile[tyy+8*j][txx] = Wrec[(size_t)(by*32 + tyy+8*j)*N_NEU + bx*32 + txx];
    __syncthreads();
    #pragma unroll
    for(int j=0;j<4;j++)
        Wt[(size_t)(bx*32 + tyy+8*j)*N_NEU + by*32 + txx] = tile[txx][tyy+8*j];
}

// ---------------- input projection GEMM (fp64 accum, fp32 LDS) ----------------
// projG[b][t][iidx[c]] = sum_k X[t*64+b][k] * Win[c][k]   (other n stay zero)
__global__ __launch_bounds__(256) void k_proj(const float* __restrict__ X, const float* __restrict__ Win,
                                              const int* __restrict__ iidx, double* __restrict__ projG){
    __shared__ float As[32][68];
    __shared__ float Bs[32][68];
    const int r0 = blockIdx.x * 64;          // 64 rows == one t
    const int c0 = blockIdx.y * 64;
    const int t  = threadIdx.x;
    const int lr = t >> 2;          // 0..63
    const int lk = (t & 3) * 8;     // 0,8,16,24
    const int tx = t & 15, ty = t >> 4;
    double acc[4][4] = {};
    for(int k0 = 0; k0 < KIN; k0 += 32){
        int kk = k0 + lk;
        float a8[8], b8[8];
        if(kk + 8 <= KIN){
            const float* pa = X   + (size_t)(r0+lr)*KIN + kk;
            const float* pb = Win + (size_t)(c0+lr)*KIN + kk;
            float4 ra0 = *reinterpret_cast<const float4*>(pa);
            float4 ra1 = *reinterpret_cast<const float4*>(pa + 4);
            float4 rb0 = *reinterpret_cast<const float4*>(pb);
            float4 rb1 = *reinterpret_cast<const float4*>(pb + 4);
            a8[0]=ra0.x; a8[1]=ra0.y; a8[2]=ra0.z; a8[3]=ra0.w;
            a8[4]=ra1.x; a8[5]=ra1.y; a8[6]=ra1.z; a8[7]=ra1.w;
            b8[0]=rb0.x; b8[1]=rb0.y; b8[2]=rb0.z; b8[3]=rb0.w;
            b8[4]=rb1.x; b8[5]=rb1.y; b8[6]=rb1.z; b8[7]=rb1.w;
        } else {
            #pragma unroll
            for(int e=0;e<8;e++){ a8[e]=0.0f; b8[e]=0.0f; }
        }
        #pragma unroll
        for(int e=0;e<8;e++){ As[lk+e][lr] = a8[e]; Bs[lk+e][lr] = b8[e]; }
        __syncthreads();
        #pragma unroll
        for(int kkk=0;kkk<32;kkk++){
            float4 af = *reinterpret_cast<const float4*>(&As[kkk][ty*4]);
            float4 bf = *reinterpret_cast<const float4*>(&Bs[kkk][tx*4]);
            double a[4] = {(double)af.x,(double)af.y,(double)af.z,(double)af.w};
            double b[4] = {(double)bf.x,(double)bf.y,(double)bf.z,(double)bf.w};
            #pragma unroll
            for(int i=0;i<4;i++)
                #pragma unroll
                for(int j=0;j<4;j++)
                    acc[i][j] += a[i]*b[j];
        }
        __syncthreads();
    }
    const int tt = blockIdx.x;
    #pragma unroll
    for(int j=0;j<4;j++){
        int c = c0 + tx*4 + j;
        int n = iidx[c];
        #pragma unroll
        for(int i=0;i<4;i++){
            int b = ty*4 + i;
            projG[((size_t)b*TT + tt)*N_NEU + n] = acc[i][j];
        }
    }
}

// ---------------- per-(batch,half) simulation: 128 blocks x 1024 threads ----------------
// Block bid = b*2 + h owns batch b, neurons [h*1024, h*1024+1024). Thread updates 1 neuron.
// Per-step spike halves exchanged via self-tagged parity mailboxes (device-scope atomics).
// Max skew between pair blocks is 1 step (data dependence), so 2 parity slots suffice.
__global__ __launch_bounds__(1024) void k_sim(
        const double* __restrict__ projG, const float* __restrict__ Wt,
        const double* __restrict__ dsyn, const double* __restrict__ etau,
        u64* __restrict__ exch, double* __restrict__ cntout){
    __shared__ double Ip[4][1024];    // 32 KB gather partials for local half
    __shared__ u32 words[64];         // full-network spike bitmask (ascending order)
    __shared__ u16 list[N_NEU];       // ordered spike list
    __shared__ int cntS;

    const int bid = blockIdx.x;
    const int b   = bid >> 1;
    const int h   = bid & 1;
    const int tid = threadIdx.x;
    const int n   = h*1024 + tid;          // neuron this thread updates
    const int team = tid >> 8;             // 0..3 gather teams
    const int nq   = (tid & 255) * 4;      // gather cols [nq,nq+4) within my half
    const float*  WtH   = Wt + h*1024;
    const double* projB = projG + (size_t)b*TT*N_NEU + h*1024;

    u64* myE = exch + (size_t)bid*2*32;                  // my [parity][32] mailbox
    u64* prE = exch + (size_t)(b*2 + (1-h))*2*32;        // partner's

    const double ds = dsyn[n], et = etau[n];
    const double dasc = exp(-0.0125);
    double v=-60.0, psc=0.0, rise=0.0, asc=0.0, ref=0.0, spk=0.0, creg=0.0;

    if(tid == 0) cntS = 0;
    __syncthreads();

    for(int t=0;t<TT;t++){
        double pp = projB[(size_t)t*N_NEU + tid];

        // ---- gather over my quarter of the ordered spike list ----
        const int cc  = cntS;
        const int beg = (cc * team)     >> 2;
        const int end = (cc * (team+1)) >> 2;
        double I[4] = {0.0, 0.0, 0.0, 0.0};
        int i = beg;
        for(; i + 8 <= end; i += 8){
            int m[8];
            #pragma unroll
            for(int u=0;u<8;u++) m[u] = list[i+u];
            float4 wv[8];
            #pragma unroll
            for(int u=0;u<8;u++)
                wv[u] = *reinterpret_cast<const float4*>(WtH + ((size_t)m[u] << 11) + nq);
            #pragma unroll
            for(int u=0;u<8;u++){
                I[0] += (double)wv[u].x; I[1] += (double)wv[u].y;
                I[2] += (double)wv[u].z; I[3] += (double)wv[u].w;
            }
        }
        for(; i < end; ++i){
            int mm = list[i];
            float4 w4 = *reinterpret_cast<const float4*>(WtH + ((size_t)mm << 11) + nq);
            I[0] += (double)w4.x; I[1] += (double)w4.y;
            I[2] += (double)w4.z; I[3] += (double)w4.w;
        }
        #pragma unroll
        for(int u=0;u<4;u++) Ip[team][nq+u] = I[u];
        __syncthreads();

        // ---- combine partials (fixed order q0+q1+q2+q3) + external drive ----
        double Irec = Ip[0][tid] + Ip[1][tid] + Ip[2][tid] + Ip[3][tid] + pp;

        // ---- neuron update (verified arithmetic, unchanged) ----
        double psc_n  = ds * (psc + rise);
        double rise_n = ds * rise + et * Irec;
        double asc_n  = dasc * asc + (-0.2) * spk;
        double act    = (ref <= 0.0) ? 1.0 : 0.0;
        double dv  = (psc_n + asc_n + 0.12) / 2.0 - (v - (-60.0)) / 20.0;
        double v_n = v + act * dv;
        double s_n = ((v_n - (-45.0)) >= 0.0) ? act : 0.0;
        v_n = v_n - s_n * 15.0;
        double ref_n = (s_n > 0.0) ? 2.0 : fmax(ref - 1.0, 0.0);
        v = v_n; psc = psc_n; rise = rise_n; asc = asc_n; ref = ref_n; spk = s_n;
        creg += s_n;

        // ---- publish own ballots: LDS words + tagged mailbox ----
        u64 bal = __ballot(s_n > 0.0);
        int w = tid >> 6, lane = tid & 63;
        u64 tagv = ((u64)(t+1)) << 32;
        if(lane == 0){
            u32 lo = (u32)bal, hi = (u32)(bal >> 32);
            words[h*32 + 2*w]     = lo;
            words[h*32 + 2*w + 1] = hi;
            u64* dst = myE + (size_t)(t & 1)*32;
            __hip_atomic_store(&dst[2*w],     tagv | lo, __ATOMIC_RELEASE, __HIP_MEMORY_SCOPE_AGENT);
            __hip_atomic_store(&dst[2*w + 1], tagv | hi, __ATOMIC_RELEASE, __HIP_MEMORY_SCOPE_AGENT);
        }
        // ---- poll partner's 32 tagged words ----
        if(tid < 32){
            const u64* src = prE + (size_t)(t & 1)*32;
            u64 val;
            while(true){
                val = __hip_atomic_load(&src[tid], __ATOMIC_ACQUIRE, __HIP_MEMORY_SCOPE_AGENT);
                if((val >> 32) == (u64)(t+1)) break;
                __builtin_amdgcn_s_sleep(1);
            }
            words[(1-h)*32 + tid] = (u32)val;
        }
        __syncthreads();

        // ---- wave 0: ordered compaction of full-network words into list ----
        if(tid < 64){
            u32 wv = words[tid];
            int c = __popc(wv);
            int incl = c;
            #pragma unroll
            for(int off=1; off<64; off<<=1){
                int x = __shfl_up(incl, off);
                if(tid >= off) incl += x;
            }
            int excl = incl - c;
            u32 z = wv;
            int base = tid * 32;
            while(z){
                int bp = __ffs(z) - 1;
                z &= z - 1;
                list[excl++] = (u16)(base + bp);
            }
            if(tid == 63) cntS = incl;
        }
        __syncthreads();
    }

    cntout[(size_t)b*N_NEU + n] = creg;
}

// ---------------- readout ----------------
__global__ void k_final(const double* __restrict__ cnt, const int* __restrict__ oidx,
                        const float* __restrict__ Wout, float* __restrict__ out){
    int i = blockIdx.x * blockDim.x + threadIdx.x;
    if(i >= BB * N_OUT) return;
    int b = i / N_OUT, o = i - b * N_OUT;
    double accv = 0.0;
    for(int j=0;j<NOUT_NEU;j++){
        double rate = cnt[(size_t)b*N_NEU + oidx[j]] / 100.0;
        accv += rate * (double)Wout[o*NOUT_NEU + j];
    }
    out[i] = (float)accv;
}

extern "C" void kernel_launch(void* const* d_in, const int* in_sizes, int n_in,
                              void* d_out, int out_size, void* d_ws, size_t ws_size,
                              hipStream_t stream){
    const float* X    = (const float*)d_in[0];
    const float* Win  = (const float*)d_in[1];
    const float* Wrec = (const float*)d_in[2];
    const float* Wout = (const float*)d_in[3];
    const float* tau  = (const float*)d_in[4];
    const int*   iidx = (const int*)d_in[5];
    const int*   oidx = (const int*)d_in[6];
    float* out = (float*)d_out;

    char* w = (char*)d_ws;
    const size_t OFF_PROJG = 0;                                     // 104,857,600
    const size_t OFF_CNT   = OFF_PROJG + (size_t)BB*TT*N_NEU*8;     // 1,048,576
    const size_t OFF_WT    = OFF_CNT + (size_t)BB*N_NEU*8;          // 16,777,216
    const size_t OFF_EXCH  = OFF_WT + (size_t)N_NEU*N_NEU*4;        // 65,536
    const size_t OFF_DS    = OFF_EXCH + 65536;
    const size_t OFF_ET    = OFF_DS + N_NEU*8;

    double* projG = (double*)(w + OFF_PROJG);
    double* cnt   = (double*)(w + OFF_CNT);
    float*  Wt    = (float*)(w + OFF_WT);
    u64*    exch  = (u64*)(w + OFF_EXCH);
    double* dsyn  = (double*)(w + OFF_DS);
    double* etau  = (double*)(w + OFF_ET);

    k_prep <<<dim3(8),      dim3(256),  0, stream>>>(tau, dsyn, etau);
    k_zero <<<dim3(4096),   dim3(256),  0, stream>>>(projG, (long)BB*TT*N_NEU, exch, 8192);
    k_tr   <<<dim3(64,64),  dim3(32,8), 0, stream>>>(Wrec, Wt);
    k_proj <<<dim3(100,16), dim3(256),  0, stream>>>(X, Win, iidx, projG);
    k_sim  <<<dim3(2*BB),   dim3(1024), 0, stream>>>(projG, Wt, dsyn, etau, exch, cnt);
    k_final<<<dim3(3),      dim3(256),  0, stream>>>(cnt, oidx, Wout, out);
}

// Round 8
// 669.666 us; speedup vs baseline: 8.8969x; 8.8969x over previous
//
#include <hip/hip_runtime.h>
#include <math.h>

#define N_NEU    2048
#define BB       64
#define TT       100
#define KIN      784
#define NIN_NEU  1024
#define N_OUT    10
#define NOUT_NEU 128

typedef unsigned int u32;
typedef unsigned long long u64;
typedef unsigned short u16;

// ---------------- prep ----------------
__global__ void k_prep(const float* __restrict__ tau, double* __restrict__ d_syn,
                       double* __restrict__ e_tau){
    int n = blockIdx.x * blockDim.x + threadIdx.x;
    if(n < N_NEU){
        double tv = (double)tau[n];
        d_syn[n] = exp(-1.0 / tv);
        e_tau[n] = 2.718281828459045 / tv;   // np.e / tau
    }
}

// zero projG + exch (ws is poisoned 0xAA; exch tags MUST be 0 at every launch)
__global__ void k_zero(double* __restrict__ p, long nels, u64* __restrict__ exch, int nexch){
    long i = (long)blockIdx.x * blockDim.x + threadIdx.x;
    long stride = (long)gridDim.x * blockDim.x;
    for(; i < nels; i += stride) p[i] = 0.0;
    int j = blockIdx.x * blockDim.x + threadIdx.x;
    if(j < nexch) exch[j] = 0ull;
}

// ---------------- W transpose: Wt[m][n] = Wrec[n][m] ----------------
__global__ __launch_bounds__(256) void k_tr(const float* __restrict__ Wrec, float* __restrict__ Wt){
    __shared__ float tile[32][33];
    int bx = blockIdx.x, by = blockIdx.y;
    int txx = threadIdx.x, tyy = threadIdx.y;          // (32, 8)
    #pragma unroll
    for(int j=0;j<4;j++)
        tile[tyy+8*j][txx] = Wrec[(size_t)(by*32 + tyy+8*j)*N_NEU + bx*32 + txx];
    __syncthreads();
    #pragma unroll
    for(int j=0;j<4;j++)
        Wt[(size_t)(bx*32 + tyy+8*j)*N_NEU + by*32 + txx] = tile[txx][tyy+8*j];
}

// ---------------- input projection GEMM (fp64 accum, fp32 LDS) ----------------
// projG[b][t][iidx[c]] = sum_k X[t*64+b][k] * Win[c][k]   (other n stay zero)
__global__ __launch_bounds__(256) void k_proj(const float* __restrict__ X, const float* __restrict__ Win,
                                              const int* __restrict__ iidx, double* __restrict__ projG){
    __shared__ float As[32][68];
    __shared__ float Bs[32][68];
    const int r0 = blockIdx.x * 64;          // 64 rows == one t
    const int c0 = blockIdx.y * 64;
    const int t  = threadIdx.x;
    const int lr = t >> 2;          // 0..63
    const int lk = (t & 3) * 8;     // 0,8,16,24
    const int tx = t & 15, ty = t >> 4;
    double acc[4][4] = {};
    for(int k0 = 0; k0 < KIN; k0 += 32){
        int kk = k0 + lk;
        float a8[8], b8[8];
        if(kk + 8 <= KIN){
            const float* pa = X   + (size_t)(r0+lr)*KIN + kk;
            const float* pb = Win + (size_t)(c0+lr)*KIN + kk;
            float4 ra0 = *reinterpret_cast<const float4*>(pa);
            float4 ra1 = *reinterpret_cast<const float4*>(pa + 4);
            float4 rb0 = *reinterpret_cast<const float4*>(pb);
            float4 rb1 = *reinterpret_cast<const float4*>(pb + 4);
            a8[0]=ra0.x; a8[1]=ra0.y; a8[2]=ra0.z; a8[3]=ra0.w;
            a8[4]=ra1.x; a8[5]=ra1.y; a8[6]=ra1.z; a8[7]=ra1.w;
            b8[0]=rb0.x; b8[1]=rb0.y; b8[2]=rb0.z; b8[3]=rb0.w;
            b8[4]=rb1.x; b8[5]=rb1.y; b8[6]=rb1.z; b8[7]=rb1.w;
        } else {
            #pragma unroll
            for(int e=0;e<8;e++){ a8[e]=0.0f; b8[e]=0.0f; }
        }
        #pragma unroll
        for(int e=0;e<8;e++){ As[lk+e][lr] = a8[e]; Bs[lk+e][lr] = b8[e]; }
        __syncthreads();
        #pragma unroll
        for(int kkk=0;kkk<32;kkk++){
            float4 af = *reinterpret_cast<const float4*>(&As[kkk][ty*4]);
            float4 bf = *reinterpret_cast<const float4*>(&Bs[kkk][tx*4]);
            double a[4] = {(double)af.x,(double)af.y,(double)af.z,(double)af.w};
            double b[4] = {(double)bf.x,(double)bf.y,(double)bf.z,(double)bf.w};
            #pragma unroll
            for(int i=0;i<4;i++)
                #pragma unroll
                for(int j=0;j<4;j++)
                    acc[i][j] += a[i]*b[j];
        }
        __syncthreads();
    }
    const int tt = blockIdx.x;
    #pragma unroll
    for(int j=0;j<4;j++){
        int c = c0 + tx*4 + j;
        int n = iidx[c];
        #pragma unroll
        for(int i=0;i<4;i++){
            int b = ty*4 + i;
            projG[((size_t)b*TT + tt)*N_NEU + n] = acc[i][j];
        }
    }
}

// ---------------- per-(batch,quarter) simulation: 256 blocks x 512 threads ----------------
// Block bid = b*4 + q owns batch b, neurons [q*512, q*512+512). Thread updates 1 neuron.
// Spike quarters exchanged via tag+payload u64 packets using RMW atomics only
// (RMWs execute at the cross-XCD-coherent point; no acquire/release cache maintenance).
// Max skew between sibling blocks is 1 step, so 2 parity slots suffice.
__global__ __launch_bounds__(512) void k_sim(
        const double* __restrict__ projG, const float* __restrict__ Wt,
        const double* __restrict__ dsyn, const double* __restrict__ etau,
        u64* __restrict__ exch, double* __restrict__ cntout){
    __shared__ double Ip[4][512];     // 16 KB gather partials for my 512 columns
    __shared__ u32 words[64];         // full-network spike bitmask (ascending order)
    __shared__ u16 list[N_NEU];       // ordered spike list
    __shared__ int cntS;

    const int bid = blockIdx.x;
    const int b   = bid >> 2;
    const int q   = bid & 3;
    const int tid = threadIdx.x;
    const int n   = q*512 + tid;           // neuron this thread updates
    const int team = tid >> 7;             // 0..3 gather teams (list quarters)
    const int c4   = (tid & 127) * 4;      // gather cols [c4,c4+4) within my 512
    const float*  WtQ   = Wt + q*512;
    const double* projB = projG + (size_t)b*TT*N_NEU + q*512;

    u64* myE = exch + (size_t)bid*32;      // my [parity(2)][16] mailbox

    const double ds = dsyn[n], et = etau[n];
    const double dasc = exp(-0.0125);
    double v=-60.0, psc=0.0, rise=0.0, asc=0.0, ref=0.0, spk=0.0, creg=0.0;

    if(tid == 0) cntS = 0;
    __syncthreads();

    for(int t=0;t<TT;t++){
        double pp = projB[(size_t)t*N_NEU + tid];

        // ---- gather over my quarter of the ordered spike list, cols [c4,c4+4) ----
        const int cc  = cntS;
        const int beg = (cc * team)     >> 2;
        const int end = (cc * (team+1)) >> 2;
        double I[4] = {0.0, 0.0, 0.0, 0.0};
        int i = beg;
        for(; i + 8 <= end; i += 8){
            int m[8];
            #pragma unroll
            for(int u=0;u<8;u++) m[u] = list[i+u];
            float4 wv[8];
            #pragma unroll
            for(int u=0;u<8;u++)
                wv[u] = *reinterpret_cast<const float4*>(WtQ + ((size_t)m[u] << 11) + c4);
            #pragma unroll
            for(int u=0;u<8;u++){
                I[0] += (double)wv[u].x; I[1] += (double)wv[u].y;
                I[2] += (double)wv[u].z; I[3] += (double)wv[u].w;
            }
        }
        for(; i < end; ++i){
            int mm = list[i];
            float4 w4 = *reinterpret_cast<const float4*>(WtQ + ((size_t)mm << 11) + c4);
            I[0] += (double)w4.x; I[1] += (double)w4.y;
            I[2] += (double)w4.z; I[3] += (double)w4.w;
        }
        #pragma unroll
        for(int u=0;u<4;u++) Ip[team][c4+u] = I[u];
        __syncthreads();

        // ---- combine partials (fixed order q0+q1+q2+q3) + external drive ----
        double Irec = Ip[0][tid] + Ip[1][tid] + Ip[2][tid] + Ip[3][tid] + pp;

        // ---- neuron update (verified arithmetic, unchanged) ----
        double psc_n  = ds * (psc + rise);
        double rise_n = ds * rise + et * Irec;
        double asc_n  = dasc * asc + (-0.2) * spk;
        double act    = (ref <= 0.0) ? 1.0 : 0.0;
        double dv  = (psc_n + asc_n + 0.12) / 2.0 - (v - (-60.0)) / 20.0;
        double v_n = v + act * dv;
        double s_n = ((v_n - (-45.0)) >= 0.0) ? act : 0.0;
        v_n = v_n - s_n * 15.0;
        double ref_n = (s_n > 0.0) ? 2.0 : fmax(ref - 1.0, 0.0);
        v = v_n; psc = psc_n; rise = rise_n; asc = asc_n; ref = ref_n; spk = s_n;
        creg += s_n;

        // ---- publish own ballots: LDS words + tagged mailbox (atomicExch RMW) ----
        u64 bal = __ballot(s_n > 0.0);
        int w = tid >> 6, lane = tid & 63;     // wave w covers neurons [512q+64w, +64)
        u64 tagv = ((u64)(t+1)) << 32;
        if(lane == 0){
            u32 lo = (u32)bal, hi = (u32)(bal >> 32);
            words[q*16 + 2*w]     = lo;
            words[q*16 + 2*w + 1] = hi;
            u64* dst = myE + (size_t)(t & 1)*16;
            atomicExch(&dst[2*w],     tagv | (u64)lo);
            atomicExch(&dst[2*w + 1], tagv | (u64)hi);
        }
        // ---- poll 3 siblings' 16 tagged words each (atomicAdd(·,0) = coherent read) ----
        if(tid < 48){
            int pidx = tid >> 4;               // 0..2
            int w2   = tid & 15;
            int q2   = pidx + (pidx >= q ? 1 : 0);
            u64* src = exch + (size_t)(b*4 + q2)*32 + (size_t)(t & 1)*16;
            u64 val = atomicAdd(&src[w2], 0ull);
            while((val >> 32) != (u64)(t+1)){
                __builtin_amdgcn_s_sleep(1);
                val = atomicAdd(&src[w2], 0ull);
            }
            words[q2*16 + w2] = (u32)val;
        }
        __syncthreads();

        // ---- wave 0: ordered compaction of full-network words into list ----
        if(tid < 64){
            u32 wv = words[tid];
            int c = __popc(wv);
            int incl = c;
            #pragma unroll
            for(int off=1; off<64; off<<=1){
                int x = __shfl_up(incl, off);
                if(tid >= off) incl += x;
            }
            int excl = incl - c;
            u32 z = wv;
            int base = tid * 32;
            while(z){
                int bp = __ffs(z) - 1;
                z &= z - 1;
                list[excl++] = (u16)(base + bp);
            }
            if(tid == 63) cntS = incl;
        }
        __syncthreads();
    }

    cntout[(size_t)b*N_NEU + n] = creg;
}

// ---------------- readout ----------------
__global__ void k_final(const double* __restrict__ cnt, const int* __restrict__ oidx,
                        const float* __restrict__ Wout, float* __restrict__ out){
    int i = blockIdx.x * blockDim.x + threadIdx.x;
    if(i >= BB * N_OUT) return;
    int b = i / N_OUT, o = i - b * N_OUT;
    double accv = 0.0;
    for(int j=0;j<NOUT_NEU;j++){
        double rate = cnt[(size_t)b*N_NEU + oidx[j]] / 100.0;
        accv += rate * (double)Wout[o*NOUT_NEU + j];
    }
    out[i] = (float)accv;
}

extern "C" void kernel_launch(void* const* d_in, const int* in_sizes, int n_in,
                              void* d_out, int out_size, void* d_ws, size_t ws_size,
                              hipStream_t stream){
    const float* X    = (const float*)d_in[0];
    const float* Win  = (const float*)d_in[1];
    const float* Wrec = (const float*)d_in[2];
    const float* Wout = (const float*)d_in[3];
    const float* tau  = (const float*)d_in[4];
    const int*   iidx = (const int*)d_in[5];
    const int*   oidx = (const int*)d_in[6];
    float* out = (float*)d_out;

    char* w = (char*)d_ws;
    const size_t OFF_PROJG = 0;                                     // 104,857,600
    const size_t OFF_CNT   = OFF_PROJG + (size_t)BB*TT*N_NEU*8;     // 1,048,576
    const size_t OFF_WT    = OFF_CNT + (size_t)BB*N_NEU*8;          // 16,777,216
    const size_t OFF_EXCH  = OFF_WT + (size_t)N_NEU*N_NEU*4;        // 65,536
    const size_t OFF_DS    = OFF_EXCH + 65536;
    const size_t OFF_ET    = OFF_DS + N_NEU*8;

    double* projG = (double*)(w + OFF_PROJG);
    double* cnt   = (double*)(w + OFF_CNT);
    float*  Wt    = (float*)(w + OFF_WT);
    u64*    exch  = (u64*)(w + OFF_EXCH);
    double* dsyn  = (double*)(w + OFF_DS);
    double* etau  = (double*)(w + OFF_ET);

    k_prep <<<dim3(8),      dim3(256),  0, stream>>>(tau, dsyn, etau);
    k_zero <<<dim3(4096),   dim3(256),  0, stream>>>(projG, (long)BB*TT*N_NEU, exch, 8192);
    k_tr   <<<dim3(64,64),  dim3(32,8), 0, stream>>>(Wrec, Wt);
    k_proj <<<dim3(100,16), dim3(256),  0, stream>>>(X, Win, iidx, projG);
    k_sim  <<<dim3(4*BB),   dim3(512),  0, stream>>>(projG, Wt, dsyn, etau, exch, cnt);
    k_final<<<dim3(3),      dim3(256),  0, stream>>>(cnt, oidx, Wout, out);
}

// Round 10
// 573.528 us; speedup vs baseline: 10.3882x; 1.1676x over previous
//
#include <hip/hip_runtime.h>
#include <math.h>

#define N_NEU    2048
#define BB       64
#define TT       100
#define KIN      784
#define NIN_NEU  1024
#define N_OUT    10
#define NOUT_NEU 128

typedef unsigned int u32;
typedef unsigned long long u64;
typedef unsigned short u16;
typedef double f64x4 __attribute__((ext_vector_type(4)));

// ---------------- prep ----------------
__global__ void k_prep(const float* __restrict__ tau, double* __restrict__ d_syn,
                       double* __restrict__ e_tau, int* __restrict__ inv){
    int n = blockIdx.x * blockDim.x + threadIdx.x;
    if(n < N_NEU){
        double tv = (double)tau[n];
        d_syn[n] = exp(-1.0 / tv);
        e_tau[n] = 2.718281828459045 / tv;   // np.e / tau
        inv[n] = -1;
    }
}

__global__ void k_scatter(const int* __restrict__ idx, int* __restrict__ inv){
    int j = blockIdx.x * blockDim.x + threadIdx.x;
    if(j < NIN_NEU) inv[idx[j]] = j;
}

// zero exch mailboxes (ws is poisoned 0xAA; tags MUST be 0 at every launch)
__global__ void k_zero(u64* __restrict__ exch, int nexch){
    int j = blockIdx.x * blockDim.x + threadIdx.x;
    if(j < nexch) exch[j] = 0ull;
}

// ---------------- f64 MFMA layout probe (1 wave) ----------------
// A[i][k] = 4i+k+1 staged as lane = i + 16k; B[k][j] = 16k+j+1 staged as lane = j + 16k.
// Exact integer fp64 product; validate candidate D mappings:
//   cand0: i = 4*(lane>>4) + reg ; cand1: i = (lane>>4) + 4*reg   (col = lane&15 in both).
// flag = 0 / 1 if a candidate fully matches (validates A+B+D composite); 2 = neither.
__global__ void k_probe(int* __restrict__ flag){
    int l = threadIdx.x & 63;
    double a = (double)((l & 15)*4 + (l >> 4) + 1);
    double b = (double)((l >> 4)*16 + (l & 15) + 1);
    f64x4 acc = {0.0, 0.0, 0.0, 0.0};
    acc = __builtin_amdgcn_mfma_f64_16x16x4f64(a, b, acc, 0, 0, 0);
    bool oka = true, okb = true;
    int j = l & 15;
    #pragma unroll
    for(int r=0;r<4;r++){
        int ia = 4*(l >> 4) + r;
        int ib = (l >> 4) + 4*r;
        double expA = 0.0, expB = 0.0;
        #pragma unroll
        for(int k=0;k<4;k++){
            expA += (double)((4*ia + k + 1) * (16*k + j + 1));
            expB += (double)((4*ib + k + 1) * (16*k + j + 1));
        }
        oka = oka && (acc[r] == expA);
        okb = okb && (acc[r] == expB);
    }
    bool alla = __all(oka), allb = __all(okb);
    if(threadIdx.x == 0) *flag = alla ? 0 : (allb ? 1 : 2);
}

// ---------------- W transpose: Wt[m][n] = Wrec[n][m] ----------------
__global__ __launch_bounds__(256) void k_tr(const float* __restrict__ Wrec, float* __restrict__ Wt){
    __shared__ float tile[32][33];
    int bx = blockIdx.x, by = blockIdx.y;
    int txx = threadIdx.x, tyy = threadIdx.y;          // (32, 8)
    #pragma unroll
    for(int j=0;j<4;j++)
        tile[tyy+8*j][txx] = Wrec[(size_t)(by*32 + tyy+8*j)*N_NEU + bx*32 + txx];
    __syncthreads();
    #pragma unroll
    for(int j=0;j<4;j++)
        Wt[(size_t)(bx*32 + tyy+8*j)*N_NEU + by*32 + txx] = tile[txx][tyy+8*j];
}

// ---------------- input projection GEMM via f64 MFMA (runs iff flag<2) ----------------
// projC[b][t][c] = sum_k X[t*64+b][k] * Win[c][k]
__global__ __launch_bounds__(256) void k_proj_mfma(const float* __restrict__ X, const float* __restrict__ Win,
                                                   const int* __restrict__ flagp, double* __restrict__ projC){
    const int flag = *flagp;
    if(flag >= 2) return;
    __shared__ float As[32][81];   // As[k][row]
    __shared__ float Bs[32][81];   // Bs[k][col]
    const int t   = blockIdx.x;
    const int c0  = blockIdx.y * 64;
    const int tid = threadIdx.x;
    const int w   = tid >> 6;
    const int l   = tid & 63;
    const int g   = l >> 4;
    const int cl  = l & 15;
    const int lr  = tid >> 2;
    const int lk  = (tid & 3) * 8;

    f64x4 acc[4] = {{0.,0.,0.,0.},{0.,0.,0.,0.},{0.,0.,0.,0.},{0.,0.,0.,0.}};

    for(int k0 = 0; k0 < KIN; k0 += 32){
        int kk = k0 + lk;
        float a8[8], b8[8];
        if(kk + 8 <= KIN){
            const float* pa = X   + (size_t)(t*64 + lr)*KIN + kk;
            const float* pb = Win + (size_t)(c0 + lr)*KIN + kk;
            float4 ra0 = *reinterpret_cast<const float4*>(pa);
            float4 ra1 = *reinterpret_cast<const float4*>(pa + 4);
            float4 rb0 = *reinterpret_cast<const float4*>(pb);
            float4 rb1 = *reinterpret_cast<const float4*>(pb + 4);
            a8[0]=ra0.x; a8[1]=ra0.y; a8[2]=ra0.z; a8[3]=ra0.w;
            a8[4]=ra1.x; a8[5]=ra1.y; a8[6]=ra1.z; a8[7]=ra1.w;
            b8[0]=rb0.x; b8[1]=rb0.y; b8[2]=rb0.z; b8[3]=rb0.w;
            b8[4]=rb1.x; b8[5]=rb1.y; b8[6]=rb1.z; b8[7]=rb1.w;
        } else {
            #pragma unroll
            for(int e=0;e<8;e++){ a8[e]=0.0f; b8[e]=0.0f; }
        }
        #pragma unroll
        for(int e=0;e<8;e++){ As[lk+e][lr] = a8[e]; Bs[lk+e][lr] = b8[e]; }
        __syncthreads();

        #pragma unroll
        for(int kq=0;kq<8;kq++){
            double a = (double)As[kq*4 + g][w*16 + cl];
            #pragma unroll
            for(int ct=0;ct<4;ct++){
                double bb = (double)Bs[kq*4 + g][ct*16 + cl];
                acc[ct] = __builtin_amdgcn_mfma_f64_16x16x4f64(a, bb, acc[ct], 0, 0, 0);
            }
        }
        __syncthreads();
    }

    #pragma unroll
    for(int ct=0;ct<4;ct++){
        int c = c0 + ct*16 + cl;
        #pragma unroll
        for(int j=0;j<4;j++){
            int b = w*16 + ((flag == 0) ? (4*g + j) : (g + 4*j));
            projC[((size_t)b*TT + t)*NIN_NEU + c] = acc[ct][j];
        }
    }
}

// ---------------- VALU fallback projection (runs iff flag==2); round-8-verified loop ----------------
__global__ __launch_bounds__(256) void k_proj_valu(const float* __restrict__ X, const float* __restrict__ Win,
                                                   const int* __restrict__ flagp, double* __restrict__ projC){
    if(*flagp < 2) return;
    __shared__ float As[32][68];
    __shared__ float Bs[32][68];
    const int r0 = blockIdx.x * 64;
    const int c0 = blockIdx.y * 64;
    const int t  = threadIdx.x;
    const int lr = t >> 2;
    const int lk = (t & 3) * 8;
    const int tx = t & 15, ty = t >> 4;
    double acc[4][4] = {};
    for(int k0 = 0; k0 < KIN; k0 += 32){
        int kk = k0 + lk;
        float a8[8], b8[8];
        if(kk + 8 <= KIN){
            const float* pa = X   + (size_t)(r0+lr)*KIN + kk;
            const float* pb = Win + (size_t)(c0+lr)*KIN + kk;
            float4 ra0 = *reinterpret_cast<const float4*>(pa);
            float4 ra1 = *reinterpret_cast<const float4*>(pa + 4);
            float4 rb0 = *reinterpret_cast<const float4*>(pb);
            float4 rb1 = *reinterpret_cast<const float4*>(pb + 4);
            a8[0]=ra0.x; a8[1]=ra0.y; a8[2]=ra0.z; a8[3]=ra0.w;
            a8[4]=ra1.x; a8[5]=ra1.y; a8[6]=ra1.z; a8[7]=ra1.w;
            b8[0]=rb0.x; b8[1]=rb0.y; b8[2]=rb0.z; b8[3]=rb0.w;
            b8[4]=rb1.x; b8[5]=rb1.y; b8[6]=rb1.z; b8[7]=rb1.w;
        } else {
            #pragma unroll
            for(int e=0;e<8;e++){ a8[e]=0.0f; b8[e]=0.0f; }
        }
        #pragma unroll
        for(int e=0;e<8;e++){ As[lk+e][lr] = a8[e]; Bs[lk+e][lr] = b8[e]; }
        __syncthreads();
        #pragma unroll
        for(int kkk=0;kkk<32;kkk++){
            float4 af = *reinterpret_cast<const float4*>(&As[kkk][ty*4]);
            float4 bf = *reinterpret_cast<const float4*>(&Bs[kkk][tx*4]);
            double a[4] = {(double)af.x,(double)af.y,(double)af.z,(double)af.w};
            double b[4] = {(double)bf.x,(double)bf.y,(double)bf.z,(double)bf.w};
            #pragma unroll
            for(int i=0;i<4;i++)
                #pragma unroll
                for(int j=0;j<4;j++)
                    acc[i][j] += a[i]*b[j];
        }
        __syncthreads();
    }
    const int tt = blockIdx.x;
    #pragma unroll
    for(int j=0;j<4;j++){
        int c = c0 + tx*4 + j;
        #pragma unroll
        for(int i=0;i<4;i++){
            int b = ty*4 + i;
            projC[((size_t)b*TT + tt)*NIN_NEU + c] = acc[i][j];
        }
    }
}

// ---------------- per-(batch,quarter) simulation: 256 blocks x 512 threads ----------------
__global__ __launch_bounds__(512) void k_sim(
        const double* __restrict__ projC, const float* __restrict__ Wt,
        const double* __restrict__ dsyn, const double* __restrict__ etau,
        const int* __restrict__ inv,
        u64* __restrict__ exch, double* __restrict__ cntout){
    __shared__ double Ip[4][512];
    __shared__ u32 words[64];
    __shared__ u16 list[N_NEU];
    __shared__ int cntS;

    const int bid = blockIdx.x;
    const int b   = bid >> 2;
    const int q   = bid & 3;
    const int tid = threadIdx.x;
    const int n   = q*512 + tid;
    const int team = tid >> 7;
    const int c4   = (tid & 127) * 4;
    const float*  WtQ   = Wt + q*512;
    const double* projB = projC + (size_t)b*TT*NIN_NEU;

    u64* myE = exch + (size_t)bid*32;

    const double ds = dsyn[n], et = etau[n];
    const int jv = inv[n];
    const double dasc = exp(-0.0125);
    double v=-60.0, psc=0.0, rise=0.0, asc=0.0, ref=0.0, spk=0.0, creg=0.0;

    if(tid == 0) cntS = 0;
    __syncthreads();

    for(int t=0;t<TT;t++){
        double pp = (jv >= 0) ? projB[(size_t)t*NIN_NEU + jv] : 0.0;

        const int cc  = cntS;
        const int beg = (cc * team)     >> 2;
        const int end = (cc * (team+1)) >> 2;
        double I[4] = {0.0, 0.0, 0.0, 0.0};
        int i = beg;
        for(; i + 8 <= end; i += 8){
            int m[8];
            #pragma unroll
            for(int u=0;u<8;u++) m[u] = list[i+u];
            float4 wv[8];
            #pragma unroll
            for(int u=0;u<8;u++)
                wv[u] = *reinterpret_cast<const float4*>(WtQ + ((size_t)m[u] << 11) + c4);
            #pragma unroll
            for(int u=0;u<8;u++){
                I[0] += (double)wv[u].x; I[1] += (double)wv[u].y;
                I[2] += (double)wv[u].z; I[3] += (double)wv[u].w;
            }
        }
        for(; i < end; ++i){
            int mm = list[i];
            float4 w4 = *reinterpret_cast<const float4*>(WtQ + ((size_t)mm << 11) + c4);
            I[0] += (double)w4.x; I[1] += (double)w4.y;
            I[2] += (double)w4.z; I[3] += (double)w4.w;
        }
        #pragma unroll
        for(int u=0;u<4;u++) Ip[team][c4+u] = I[u];
        __syncthreads();

        double Irec = Ip[0][tid] + Ip[1][tid] + Ip[2][tid] + Ip[3][tid] + pp;

        double psc_n  = ds * (psc + rise);
        double rise_n = ds * rise + et * Irec;
        double asc_n  = dasc * asc + (-0.2) * spk;
        double act    = (ref <= 0.0) ? 1.0 : 0.0;
        double dv  = (psc_n + asc_n + 0.12) / 2.0 - (v - (-60.0)) / 20.0;
        double v_n = v + act * dv;
        double s_n = ((v_n - (-45.0)) >= 0.0) ? act : 0.0;
        v_n = v_n - s_n * 15.0;
        double ref_n = (s_n > 0.0) ? 2.0 : fmax(ref - 1.0, 0.0);
        v = v_n; psc = psc_n; rise = rise_n; asc = asc_n; ref = ref_n; spk = s_n;
        creg += s_n;

        u64 bal = __ballot(s_n > 0.0);
        int w = tid >> 6, lane = tid & 63;
        u64 tagv = ((u64)(t+1)) << 32;
        if(lane == 0){
            u32 lo = (u32)bal, hi = (u32)(bal >> 32);
            words[q*16 + 2*w]     = lo;
            words[q*16 + 2*w + 1] = hi;
            u64* dst = myE + (size_t)(t & 1)*16;
            atomicExch(&dst[2*w],     tagv | (u64)lo);
            atomicExch(&dst[2*w + 1], tagv | (u64)hi);
        }
        if(tid < 48){
            int pidx = tid >> 4;
            int w2   = tid & 15;
            int q2   = pidx + (pidx >= q ? 1 : 0);
            u64* src = exch + (size_t)(b*4 + q2)*32 + (size_t)(t & 1)*16;
            u64 val = atomicAdd(&src[w2], 0ull);
            while((val >> 32) != (u64)(t+1)){
                __builtin_amdgcn_s_sleep(1);
                val = atomicAdd(&src[w2], 0ull);
            }
            words[q2*16 + w2] = (u32)val;
        }
        __syncthreads();

        if(tid < 64){
            u32 wv = words[tid];
            int c = __popc(wv);
            int incl = c;
            #pragma unroll
            for(int off=1; off<64; off<<=1){
                int x = __shfl_up(incl, off);
                if(tid >= off) incl += x;
            }
            int excl = incl - c;
            u32 z = wv;
            int base = tid * 32;
            while(z){
                int bp = __ffs(z) - 1;
                z &= z - 1;
                list[excl++] = (u16)(base + bp);
            }
            if(tid == 63) cntS = incl;
        }
        __syncthreads();
    }

    cntout[(size_t)b*N_NEU + n] = creg;
}

// ---------------- readout ----------------
__global__ void k_final(const double* __restrict__ cnt, const int* __restrict__ oidx,
                        const float* __restrict__ Wout, float* __restrict__ out){
    int i = blockIdx.x * blockDim.x + threadIdx.x;
    if(i >= BB * N_OUT) return;
    int b = i / N_OUT, o = i - b * N_OUT;
    double accv = 0.0;
    for(int j=0;j<NOUT_NEU;j++){
        double rate = cnt[(size_t)b*N_NEU + oidx[j]] / 100.0;
        accv += rate * (double)Wout[o*NOUT_NEU + j];
    }
    out[i] = (float)accv;
}

extern "C" void kernel_launch(void* const* d_in, const int* in_sizes, int n_in,
                              void* d_out, int out_size, void* d_ws, size_t ws_size,
                              hipStream_t stream){
    const float* X    = (const float*)d_in[0];
    const float* Win  = (const float*)d_in[1];
    const float* Wrec = (const float*)d_in[2];
    const float* Wout = (const float*)d_in[3];
    const float* tau  = (const float*)d_in[4];
    const int*   iidx = (const int*)d_in[5];
    const int*   oidx = (const int*)d_in[6];
    float* out = (float*)d_out;

    char* w = (char*)d_ws;
    const size_t OFF_PROJ = 0;                                      // 52,428,800
    const size_t OFF_CNT  = OFF_PROJ + (size_t)BB*TT*NIN_NEU*8;     // 1,048,576
    const size_t OFF_WT   = OFF_CNT + (size_t)BB*N_NEU*8;           // 16,777,216
    const size_t OFF_EXCH = OFF_WT + (size_t)N_NEU*N_NEU*4;         // 65,536
    const size_t OFF_DS   = OFF_EXCH + 65536;
    const size_t OFF_ET   = OFF_DS + N_NEU*8;
    const size_t OFF_INV  = OFF_ET + N_NEU*8;
    const size_t OFF_FLAG = OFF_INV + N_NEU*4;

    double* projC = (double*)(w + OFF_PROJ);
    double* cnt   = (double*)(w + OFF_CNT);
    float*  Wt    = (float*)(w + OFF_WT);
    u64*    exch  = (u64*)(w + OFF_EXCH);
    double* dsyn  = (double*)(w + OFF_DS);
    double* etau  = (double*)(w + OFF_ET);
    int*    inv   = (int*)(w + OFF_INV);
    int*    flag  = (int*)(w + OFF_FLAG);

    k_prep     <<<dim3(8),      dim3(256),  0, stream>>>(tau, dsyn, etau, inv);
    k_scatter  <<<dim3(4),      dim3(256),  0, stream>>>(iidx, inv);
    k_zero     <<<dim3(32),     dim3(256),  0, stream>>>(exch, 8192);
    k_probe    <<<dim3(1),      dim3(64),   0, stream>>>(flag);
    k_tr       <<<dim3(64,64),  dim3(32,8), 0, stream>>>(Wrec, Wt);
    k_proj_mfma<<<dim3(100,16), dim3(256),  0, stream>>>(X, Win, flag, projC);
    k_proj_valu<<<dim3(100,16), dim3(256),  0, stream>>>(X, Win, flag, projC);
    k_sim      <<<dim3(4*BB),   dim3(512),  0, stream>>>(projC, Wt, dsyn, etau, inv, exch, cnt);
    k_final    <<<dim3(3),      dim3(256),  0, stream>>>(cnt, oidx, Wout, out);
}